// Round 3
// baseline (163.225 us; speedup 1.0000x reference)
//
#include <hip/hip_runtime.h>
#include <hip/hip_bf16.h>
#include <math.h>

// Problem constants
#define B_SZ   1024
#define F_SZ   1024
#define NKER   100
#define DKER   5
#define CCOLS  (NKER * DKER)   // 500
#define OUTW   (F_SZ + NKER)   // 1124

#if defined(__has_builtin)
#if __has_builtin(__builtin_amdgcn_exp2f)
#define EXP2F(x) __builtin_amdgcn_exp2f(x)
#else
#define EXP2F(x) exp2f(x)
#endif
#else
#define EXP2F(x) exp2f(x)
#endif

// ---------------------------------------------------------------------------
// Kernel 1: copy x into out[:, :1024] and zero the feat region out[:, 1024:]
// ---------------------------------------------------------------------------
__global__ __launch_bounds__(320) void init_kernel(const float* __restrict__ x,
                                                   float* __restrict__ out) {
    const int row = blockIdx.x;
    const int t = threadIdx.x;
    if (t < 256) {
        const float4 v = *reinterpret_cast<const float4*>(&x[row * F_SZ + t * 4]);
        *reinterpret_cast<float4*>(&out[row * OUTW + t * 4]) = v;
    } else if (t < 256 + 25) {
        float4 z = make_float4(0.f, 0.f, 0.f, 0.f);
        *reinterpret_cast<float4*>(&out[row * OUTW + F_SZ + (t - 256) * 4]) = z;
    }
}

// ---------------------------------------------------------------------------
// Kernel 2: split-K fp32 GEMM. partial[s][c][j] = sum_{f in slice s} x[j][f]*T[f][c]
// BM=32 (c), BN=64 (j), BK=16 (f), KSLICE=256. Grid 16 x 16 x 4 = 1024 blocks
// -> 4 blocks/CU = 16 waves/CU (the round-2 version had 256 blocks = 1/SIMD,
// VALUBusy 9.5%; this is the occupancy fix).
// ---------------------------------------------------------------------------
#define BMC 32
#define BNJ 64
#define BKF 16
#define NSLICE 4
#define KSLICE (F_SZ / NSLICE)   // 256

__global__ __launch_bounds__(256) void gemm_splitk_kernel(const float* __restrict__ x,
                                                          const float* __restrict__ T,
                                                          float* __restrict__ partial) {
    __shared__ float Ts[BKF][BMC];        // [f][c]
    __shared__ float Xs[BKF][BNJ + 4];    // [f][j], +4 pad keeps b128 alignment
    const int tid = threadIdx.x;
    const int c0 = blockIdx.x * BMC;
    const int j0 = blockIdx.y * BNJ;
    const int s  = blockIdx.z;
    const int fbase = s * KSLICE;
    const int tcx = tid >> 4;    // 0..15 -> c sub-tile
    const int tjx = tid & 15;    // 0..15 -> j sub-tile

    float acc[2][4];
    #pragma unroll
    for (int a = 0; a < 2; ++a)
        #pragma unroll
        for (int b = 0; b < 4; ++b) acc[a][b] = 0.f;

    for (int f0 = fbase; f0 < fbase + KSLICE; f0 += BKF) {
        if (tid < 128) {
            const int r = tid >> 3;          // 0..15 (f)
            const int cc = (tid & 7) * 4;    // 0..28 (c)
            const int c = c0 + cc;
            float4 v;
            if (c + 3 < CCOLS) {
                v = *reinterpret_cast<const float4*>(&T[(f0 + r) * CCOLS + c]);
            } else {
                v.x = (c + 0 < CCOLS) ? T[(f0 + r) * CCOLS + c + 0] : 0.f;
                v.y = (c + 1 < CCOLS) ? T[(f0 + r) * CCOLS + c + 1] : 0.f;
                v.z = (c + 2 < CCOLS) ? T[(f0 + r) * CCOLS + c + 2] : 0.f;
                v.w = (c + 3 < CCOLS) ? T[(f0 + r) * CCOLS + c + 3] : 0.f;
            }
            *reinterpret_cast<float4*>(&Ts[r][cc]) = v;
        }
        {
            const int jr = tid >> 2;          // 0..63
            const int fc = (tid & 3) * 4;     // 0,4,8,12
            const float4 v =
                *reinterpret_cast<const float4*>(&x[(j0 + jr) * F_SZ + f0 + fc]);
            Xs[fc + 0][jr] = v.x;
            Xs[fc + 1][jr] = v.y;
            Xs[fc + 2][jr] = v.z;
            Xs[fc + 3][jr] = v.w;
        }
        __syncthreads();

        #pragma unroll
        for (int kk = 0; kk < BKF; ++kk) {
            const float a0 = Ts[kk][tcx * 2 + 0];
            const float a1 = Ts[kk][tcx * 2 + 1];
            const float4 b = *reinterpret_cast<const float4*>(&Xs[kk][tjx * 4]);
            acc[0][0] += a0 * b.x;
            acc[0][1] += a0 * b.y;
            acc[0][2] += a0 * b.z;
            acc[0][3] += a0 * b.w;
            acc[1][0] += a1 * b.x;
            acc[1][1] += a1 * b.y;
            acc[1][2] += a1 * b.z;
            acc[1][3] += a1 * b.w;
        }
        __syncthreads();
    }

    float* pbase = partial + (size_t)s * CCOLS * B_SZ;
    #pragma unroll
    for (int cc = 0; cc < 2; ++cc) {
        const int c = c0 + tcx * 2 + cc;
        if (c < CCOLS) {
            const int j = j0 + tjx * 4;
            float4 o;
            o.x = acc[cc][0];
            o.y = acc[cc][1];
            o.z = acc[cc][2];
            o.w = acc[cc][3];
            *reinterpret_cast<float4*>(&pbase[c * B_SZ + j]) = o;
        }
    }
}

// Reduce 4 K-slices and apply log2(e): mt[c][j] = LOG2E * sum_s partial[s][c][j]
__global__ __launch_bounds__(256) void reduce_kernel(const float* __restrict__ partial,
                                                     float* __restrict__ mt) {
    const float LOG2E = 1.44269504088896340736f;
    const int c = blockIdx.x;              // 0..499
    const int j = threadIdx.x * 4;         // 0..1020
    const size_t off = (size_t)c * B_SZ + j;
    float4 a = *reinterpret_cast<const float4*>(&partial[off]);
    #pragma unroll
    for (int s = 1; s < NSLICE; ++s) {
        const float4 b = *reinterpret_cast<const float4*>(&partial[(size_t)s * CCOLS * B_SZ + off]);
        a.x += b.x; a.y += b.y; a.z += b.z; a.w += b.w;
    }
    a.x *= LOG2E; a.y *= LOG2E; a.z *= LOG2E; a.w *= LOG2E;
    *reinterpret_cast<float4*>(&mt[off]) = a;
}

// ---------------------------------------------------------------------------
// Fallback single-pass GEMM (used only if ws too small for split-K partials)
// ---------------------------------------------------------------------------
__global__ __launch_bounds__(256) void gemm_kernel(const float* __restrict__ x,
                                                   const float* __restrict__ T,
                                                   float* __restrict__ mt) {
    __shared__ float Ts[BKF][BMC];
    __shared__ float Xs[BKF][BNJ + 4];
    const int tid = threadIdx.x;
    const int c0 = blockIdx.x * BMC;
    const int j0 = blockIdx.y * BNJ;
    const int tcx = tid >> 4;
    const int tjx = tid & 15;

    float acc[2][4];
    #pragma unroll
    for (int a = 0; a < 2; ++a)
        #pragma unroll
        for (int b = 0; b < 4; ++b) acc[a][b] = 0.f;

    for (int f0 = 0; f0 < F_SZ; f0 += BKF) {
        if (tid < 128) {
            const int r = tid >> 3;
            const int cc = (tid & 7) * 4;
            const int c = c0 + cc;
            float4 v;
            if (c + 3 < CCOLS) {
                v = *reinterpret_cast<const float4*>(&T[(f0 + r) * CCOLS + c]);
            } else {
                v.x = (c + 0 < CCOLS) ? T[(f0 + r) * CCOLS + c + 0] : 0.f;
                v.y = (c + 1 < CCOLS) ? T[(f0 + r) * CCOLS + c + 1] : 0.f;
                v.z = (c + 2 < CCOLS) ? T[(f0 + r) * CCOLS + c + 2] : 0.f;
                v.w = (c + 3 < CCOLS) ? T[(f0 + r) * CCOLS + c + 3] : 0.f;
            }
            *reinterpret_cast<float4*>(&Ts[r][cc]) = v;
        }
        {
            const int jr = tid >> 2;
            const int fc = (tid & 3) * 4;
            const float4 v =
                *reinterpret_cast<const float4*>(&x[(j0 + jr) * F_SZ + f0 + fc]);
            Xs[fc + 0][jr] = v.x;
            Xs[fc + 1][jr] = v.y;
            Xs[fc + 2][jr] = v.z;
            Xs[fc + 3][jr] = v.w;
        }
        __syncthreads();
        #pragma unroll
        for (int kk = 0; kk < BKF; ++kk) {
            const float a0 = Ts[kk][tcx * 2 + 0];
            const float a1 = Ts[kk][tcx * 2 + 1];
            const float4 b = *reinterpret_cast<const float4*>(&Xs[kk][tjx * 4]);
            acc[0][0] += a0 * b.x; acc[0][1] += a0 * b.y;
            acc[0][2] += a0 * b.z; acc[0][3] += a0 * b.w;
            acc[1][0] += a1 * b.x; acc[1][1] += a1 * b.y;
            acc[1][2] += a1 * b.z; acc[1][3] += a1 * b.w;
        }
        __syncthreads();
    }
    const float LOG2E = 1.44269504088896340736f;
    #pragma unroll
    for (int cc = 0; cc < 2; ++cc) {
        const int c = c0 + tcx * 2 + cc;
        if (c < CCOLS) {
            const int j = j0 + tjx * 4;
            float4 o;
            o.x = acc[cc][0] * LOG2E; o.y = acc[cc][1] * LOG2E;
            o.z = acc[cc][2] * LOG2E; o.w = acc[cc][3] * LOG2E;
            *reinterpret_cast<float4*>(&mt[c * B_SZ + j]) = o;
        }
    }
}

// ---------------------------------------------------------------------------
// Kernel 3: pairwise exp-L1. IPT=4 i-rows per thread (amortizes the 2 broadcast
// LDS reads per j over 4x the VALU), JCHUNK=128 -> grid (8, 100) = 800 blocks.
// mt pre-scaled by log2(e) -> exp2 directly.
// ---------------------------------------------------------------------------
#define JCHUNK 128
#define JSPLIT (B_SZ / JCHUNK)   // 8
#define IPT 4

__global__ __launch_bounds__(256) void pair_kernel(const float* __restrict__ mt,
                                                   float* __restrict__ out) {
    __shared__ float mj[JCHUNK][8];
    const int tid = threadIdx.x;
    const int j0 = blockIdx.x * JCHUNK;
    const int k = blockIdx.y;
    const int cbase = k * DKER;

    // stage the j-chunk: 5 x 128 floats
    for (int t = tid; t < DKER * JCHUNK; t += 256) {
        const int d = t >> 7;          // t / 128
        const int jr = t & (JCHUNK - 1);
        mj[jr][d] = mt[(cbase + d) * B_SZ + j0 + jr];
    }
    // own points: i = tid + s*256, s = 0..3 (coalesced across lanes)
    float m[IPT][DKER];
    #pragma unroll
    for (int s2 = 0; s2 < IPT; ++s2) {
        const int i = s2 * 256 + tid;
        #pragma unroll
        for (int d = 0; d < DKER; ++d)
            m[s2][d] = mt[(cbase + d) * B_SZ + i];
    }
    __syncthreads();

    float acc[IPT] = {0.f, 0.f, 0.f, 0.f};
    #pragma unroll 2
    for (int j = 0; j < JCHUNK; ++j) {
        const float4 v = *reinterpret_cast<const float4*>(&mj[j][0]);
        const float v4 = mj[j][4];
        #pragma unroll
        for (int s2 = 0; s2 < IPT; ++s2) {
            const float l = fabsf(m[s2][0] - v.x) + fabsf(m[s2][1] - v.y) +
                            fabsf(m[s2][2] - v.z) + fabsf(m[s2][3] - v.w) +
                            fabsf(m[s2][4] - v4);
            acc[s2] += EXP2F(-l);
        }
    }
    #pragma unroll
    for (int s2 = 0; s2 < IPT; ++s2) {
        const int i = s2 * 256 + tid;
        atomicAdd(&out[i * OUTW + F_SZ + k], acc[s2]);
    }
}

// ---------------------------------------------------------------------------
extern "C" void kernel_launch(void* const* d_in, const int* in_sizes, int n_in,
                              void* d_out, int out_size, void* d_ws, size_t ws_size,
                              hipStream_t stream) {
    const float* x = (const float*)d_in[0];   // [1024, 1024]
    const float* T = (const float*)d_in[1];   // [1024, 500]
    float* out = (float*)d_out;               // [1024, 1124]

    const size_t mt_bytes = (size_t)CCOLS * B_SZ * sizeof(float);           // 2 MB
    const size_t part_bytes = (size_t)NSLICE * CCOLS * B_SZ * sizeof(float); // 8 MB

    init_kernel<<<dim3(B_SZ), 320, 0, stream>>>(x, out);

    if (ws_size >= part_bytes + mt_bytes) {
        float* partial = (float*)d_ws;                      // [4][500][1024]
        float* mt = (float*)((char*)d_ws + part_bytes);     // [500][1024]
        gemm_splitk_kernel<<<dim3((CCOLS + BMC - 1) / BMC, B_SZ / BNJ, NSLICE),
                             256, 0, stream>>>(x, T, partial);
        reduce_kernel<<<dim3(CCOLS), 256, 0, stream>>>(partial, mt);
        pair_kernel<<<dim3(JSPLIT, NKER), 256, 0, stream>>>(mt, out);
    } else {
        float* mt = (float*)d_ws;
        gemm_kernel<<<dim3((CCOLS + BMC - 1) / BMC, B_SZ / BNJ), 256, 0, stream>>>(x, T, mt);
        pair_kernel<<<dim3(JSPLIT, NKER), 256, 0, stream>>>(mt, out);
    }
}